// Round 6
// baseline (478.999 us; speedup 1.0000x reference)
//
#include <hip/hip_runtime.h>
#include <hip/hip_bf16.h>
#include <math.h>

// Problem constants (from reference)
#define NN 20000      // nodes
#define NE 320000     // edges
#define FT 8          // tokens per node
#define DM 16         // embed dim
#define FD 128        // FT*DM
#define OUTC 7        // classes
#define NFD (NN * FD)
#define NPB 16        // nodes per block in node-level kernels

typedef unsigned short ushort;
typedef unsigned int uint;
typedef __fp16 h2 __attribute__((ext_vector_type(2)));  // matches amdgcn builtins
union UH { uint u; h2 h; };

__device__ inline h2 u2h(uint x) { UH c; c.u = x; return c.h; }

// fdot2: f32 += f16x2 . f16x2  (v_dot2_f32_f16)
__device__ inline float dot2(uint a, h2 b, float c) {
#if __has_builtin(__builtin_amdgcn_fdot2)
    return __builtin_amdgcn_fdot2(u2h(a), b, c, false);
#else
    h2 ah = u2h(a);
    return fmaf((float)ah.x, (float)b.x, fmaf((float)ah.y, (float)b.y, c));
#endif
}
__device__ inline float dot2u(uint a, uint b, float c) { return dot2(a, u2h(b), c); }

__device__ inline h2 pk(float a, float b) {
#if __has_builtin(__builtin_amdgcn_cvt_pkrtz)
    return __builtin_amdgcn_cvt_pkrtz(a, b);
#else
    h2 r; r.x = (__fp16)a; r.y = (__fp16)b; return r;
#endif
}
__device__ inline ushort f16b(float x) {
    union { __fp16 h; ushort u; } c; c.h = (__fp16)x; return c.u;
}

#define QSCALE 0.7213475204444817f  // 0.5 * log2(e): folds score scale + exp2 domain

// ---------------------------------------------------------------------------
// kv row layout (512B, f16 indices), per head h in 0..3 a contiguous 128B:
//   K[h] at  h*64 + g*4 + dd     (g = token 0..7, dd = head-dim 0..3)
//   V[h] at  h*64 + 32 + dd*8 + g
// Edge kernel reads one 128B block per lane: base = row + h*32 uints.
// q stored f16, pre-scaled by QSCALE, layout [f][h][dd] (= f*16 + h*4 + dd).
// ---------------------------------------------------------------------------

// Layer-1 QKV. NPB nodes per block; weights staged in LDS once.
__global__ __launch_bounds__(128) void qkv1_kernel(
    const float* __restrict__ x,
    const float* __restrict__ wqkv, const float* __restrict__ bqkv,
    ushort* __restrict__ qout, ushort* __restrict__ kvout) {
    __shared__ float sw[48 * 17];
    __shared__ float sb[48];
    __shared__ float sx[FD];
    __shared__ uint squ[64];
    __shared__ uint skvu[128];
    const int t = threadIdx.x;
    for (int i = t; i < 48 * 16; i += 128) sw[(i >> 4) * 17 + (i & 15)] = wqkv[i];
    if (t < 48) sb[t] = bqkv[t];
    const int f = t >> 4, d = t & 15, h = d >> 2, dd = d & 3;
    for (int nb = 0; nb < NPB; ++nb) {
        const int n = blockIdx.x * NPB + nb;
        __syncthreads();
        sx[t] = x[n * FD + t];
        __syncthreads();
        float aq = sb[d], ak = sb[16 + d], av = sb[32 + d];
        const float* xr = &sx[f * 16];
#pragma unroll
        for (int e = 0; e < 16; ++e) {
            const float xe = xr[e];
            aq = fmaf(xe, sw[d * 17 + e], aq);
            ak = fmaf(xe, sw[(16 + d) * 17 + e], ak);
            av = fmaf(xe, sw[(32 + d) * 17 + e], av);
        }
        ushort* sq = (ushort*)squ;
        ushort* skv = (ushort*)skvu;
        sq[t] = f16b(aq * QSCALE);
        skv[h * 64 + f * 4 + dd] = f16b(ak);          // K: dot over dd
        skv[h * 64 + 32 + dd * 8 + f] = f16b(av);     // V: dot over g(=f)
        __syncthreads();
        if (t < 64) ((uint*)(qout + n * FD))[t] = squ[t];
        ((uint*)(kvout + n * 256))[t] = skvu[t];
    }
}

// ---------------------------------------------------------------------------
// CSR build
// ---------------------------------------------------------------------------
__global__ __launch_bounds__(256) void deg_kernel(const int* __restrict__ dst,
                                                  int* __restrict__ deg) {
    const int e = blockIdx.x * 256 + threadIdx.x;
    if (e < NE) atomicAdd(&deg[dst[e]], 1);
}

__global__ __launch_bounds__(1024) void scan_kernel(const int* __restrict__ deg,
                                                    int* __restrict__ rowstart,
                                                    int* __restrict__ cursor) {
    __shared__ int wsum[16];
    __shared__ int s_carry;
    const int t = threadIdx.x;
    const int lane = t & 63, wid = t >> 6;
    if (t == 0) s_carry = 0;
    __syncthreads();
    for (int base = 0; base < NN; base += 1024) {
        const int i = base + t;
        const int d = (i < NN) ? deg[i] : 0;
        int s = d;
        for (int off = 1; off < 64; off <<= 1) {
            int tmp = __shfl_up(s, off);
            if (lane >= off) s += tmp;
        }
        if (lane == 63) wsum[wid] = s;
        __syncthreads();
        if (wid == 0) {
            int ws = (lane < 16) ? wsum[lane] : 0;
            for (int off = 1; off < 16; off <<= 1) {
                int tmp = __shfl_up(ws, off);
                if (lane >= off) ws += tmp;
            }
            if (lane < 16) wsum[lane] = ws;
        }
        __syncthreads();
        const int carry = s_carry;
        const int woff = (wid > 0) ? wsum[wid - 1] : 0;
        if (i < NN) {
            const int excl = carry + woff + s - d;
            rowstart[i] = excl;
            cursor[i] = excl;
        }
        __syncthreads();
        if (t == 1023) s_carry = carry + wsum[15];
        __syncthreads();
    }
    if (t == 0) rowstart[NN] = NE;
}

__global__ __launch_bounds__(256) void scatter_kernel(
    const int* __restrict__ src, const int* __restrict__ dst,
    int* __restrict__ cursor, int* __restrict__ csr_src) {
    const int e = blockIdx.x * 256 + threadIdx.x;
    if (e < NE) {
        const int pos = atomicAdd(&cursor[dst[e]], 1);
        csr_src[pos] = src[e];
    }
}

// ---------------------------------------------------------------------------
// Edge aggregation. One wave per dst node; 32-lane halves each run an edge
// stream with a 2-slot unroll (4 edges in flight/wave). Per lane (f,h):
// one contiguous 128B block (K then V for head h) as 8 dwordx4 from one base.
// Scores: fdot2 pairs in log2 domain; PV: fdot2 over packed-f16 e's.
// csr_src padded by 8 zeros -> branchless index prefetch; node 0's row is
// valid data so masked tail slots (invB=0) can never produce NaN.
// ---------------------------------------------------------------------------
__global__ __launch_bounds__(256) void edge_agg_kernel(
    const int* __restrict__ rowstart, const int* __restrict__ csr_src,
    const ushort* __restrict__ qh, const uint* __restrict__ kvw,
    float* __restrict__ accum) {
    const int w = (blockIdx.x * 256 + threadIdx.x) >> 6;
    if (w >= NN) return;
    const int lane = threadIdx.x & 63;
    const int hl = lane & 31, half = lane >> 5, h = hl & 3, f = hl >> 2;

    const uint2 qp = *(const uint2*)(qh + w * FD + f * 16 + h * 4);
    const int beg = rowstart[w], end = rowstart[w + 1];

    float o0 = 0.f, o1 = 0.f, o2 = 0.f, o3 = 0.f;
    int e = beg + half;
    int sA = csr_src[e];
    int sB = csr_src[e + 2];
    for (; e < end; e += 4) {
        const int cA = sA, cB = sB;
        const float mB = (e + 2 < end) ? 1.0f : 0.0f;
        sA = csr_src[e + 4];
        sB = csr_src[e + 6];

        const uint4* ka = (const uint4*)(kvw + cA * 128 + h * 32);
        const uint4* kb = (const uint4*)(kvw + cB * 128 + h * 32);
        const uint4 kA0 = ka[0], kA1 = ka[1], kA2 = ka[2], kA3 = ka[3];
        const uint4 vA0 = ka[4], vA1 = ka[5], vA2 = ka[6], vA3 = ka[7];
        const uint4 kB0 = kb[0], kB1 = kb[1], kB2 = kb[2], kB3 = kb[3];
        const uint4 vB0 = kb[4], vB1 = kb[5], vB2 = kb[6], vB3 = kb[7];

        // scores (already in log2 domain: QSCALE folded into q)
        float a0 = dot2u(qp.y, kA0.y, dot2u(qp.x, kA0.x, 0.f));
        float a1 = dot2u(qp.y, kA0.w, dot2u(qp.x, kA0.z, 0.f));
        float a2 = dot2u(qp.y, kA1.y, dot2u(qp.x, kA1.x, 0.f));
        float a3 = dot2u(qp.y, kA1.w, dot2u(qp.x, kA1.z, 0.f));
        float a4 = dot2u(qp.y, kA2.y, dot2u(qp.x, kA2.x, 0.f));
        float a5 = dot2u(qp.y, kA2.w, dot2u(qp.x, kA2.z, 0.f));
        float a6 = dot2u(qp.y, kA3.y, dot2u(qp.x, kA3.x, 0.f));
        float a7 = dot2u(qp.y, kA3.w, dot2u(qp.x, kA3.z, 0.f));
        float b0 = dot2u(qp.y, kB0.y, dot2u(qp.x, kB0.x, 0.f));
        float b1 = dot2u(qp.y, kB0.w, dot2u(qp.x, kB0.z, 0.f));
        float b2 = dot2u(qp.y, kB1.y, dot2u(qp.x, kB1.x, 0.f));
        float b3 = dot2u(qp.y, kB1.w, dot2u(qp.x, kB1.z, 0.f));
        float b4 = dot2u(qp.y, kB2.y, dot2u(qp.x, kB2.x, 0.f));
        float b5 = dot2u(qp.y, kB2.w, dot2u(qp.x, kB2.z, 0.f));
        float b6 = dot2u(qp.y, kB3.y, dot2u(qp.x, kB3.x, 0.f));
        float b7 = dot2u(qp.y, kB3.w, dot2u(qp.x, kB3.z, 0.f));

        const float mA = fmaxf(fmaxf(fmaxf(a0, a1), fmaxf(a2, a3)),
                               fmaxf(fmaxf(a4, a5), fmaxf(a6, a7)));
        const float mBm = fmaxf(fmaxf(fmaxf(b0, b1), fmaxf(b2, b3)),
                                fmaxf(fmaxf(b4, b5), fmaxf(b6, b7)));
        a0 = exp2f(a0 - mA); a1 = exp2f(a1 - mA); a2 = exp2f(a2 - mA); a3 = exp2f(a3 - mA);
        a4 = exp2f(a4 - mA); a5 = exp2f(a5 - mA); a6 = exp2f(a6 - mA); a7 = exp2f(a7 - mA);
        b0 = exp2f(b0 - mBm); b1 = exp2f(b1 - mBm); b2 = exp2f(b2 - mBm); b3 = exp2f(b3 - mBm);
        b4 = exp2f(b4 - mBm); b5 = exp2f(b5 - mBm); b6 = exp2f(b6 - mBm); b7 = exp2f(b7 - mBm);
        const float sumA = ((a0 + a1) + (a2 + a3)) + ((a4 + a5) + (a6 + a7));
        const float sumB = ((b0 + b1) + (b2 + b3)) + ((b4 + b5) + (b6 + b7));
#if __has_builtin(__builtin_amdgcn_rcpf)
        const float invA = __builtin_amdgcn_rcpf(sumA);
        const float invB = mB * __builtin_amdgcn_rcpf(sumB);
#else
        const float invA = 1.0f / sumA;
        const float invB = mB / sumB;
#endif
        // pack unnormalized e's; PV = dot over g; normalize on accumulate
        const h2 eA0 = pk(a0, a1), eA1 = pk(a2, a3), eA2 = pk(a4, a5), eA3 = pk(a6, a7);
        const h2 eB0 = pk(b0, b1), eB1 = pk(b2, b3), eB2 = pk(b4, b5), eB3 = pk(b6, b7);

        const float p0A = dot2(vA0.w, eA3, dot2(vA0.z, eA2, dot2(vA0.y, eA1, dot2(vA0.x, eA0, 0.f))));
        const float p1A = dot2(vA1.w, eA3, dot2(vA1.z, eA2, dot2(vA1.y, eA1, dot2(vA1.x, eA0, 0.f))));
        const float p2A = dot2(vA2.w, eA3, dot2(vA2.z, eA2, dot2(vA2.y, eA1, dot2(vA2.x, eA0, 0.f))));
        const float p3A = dot2(vA3.w, eA3, dot2(vA3.z, eA2, dot2(vA3.y, eA1, dot2(vA3.x, eA0, 0.f))));
        const float p0B = dot2(vB0.w, eB3, dot2(vB0.z, eB2, dot2(vB0.y, eB1, dot2(vB0.x, eB0, 0.f))));
        const float p1B = dot2(vB1.w, eB3, dot2(vB1.z, eB2, dot2(vB1.y, eB1, dot2(vB1.x, eB0, 0.f))));
        const float p2B = dot2(vB2.w, eB3, dot2(vB2.z, eB2, dot2(vB2.y, eB1, dot2(vB2.x, eB0, 0.f))));
        const float p3B = dot2(vB3.w, eB3, dot2(vB3.z, eB2, dot2(vB3.y, eB1, dot2(vB3.x, eB0, 0.f))));

        o0 = fmaf(p0A, invA, fmaf(p0B, invB, o0));
        o1 = fmaf(p1A, invA, fmaf(p1B, invB, o1));
        o2 = fmaf(p2A, invA, fmaf(p2B, invB, o2));
        o3 = fmaf(p3A, invA, fmaf(p3B, invB, o3));
    }
    o0 += __shfl_xor(o0, 32);
    o1 += __shfl_xor(o1, 32);
    o2 += __shfl_xor(o2, 32);
    o3 += __shfl_xor(o3, 32);
    if (half == 0)
        *(float4*)(accum + w * FD + hl * 4) = make_float4(o0, o1, o2, o3);
}

// ---------------------------------------------------------------------------
// Fused: h = ELU(accum @ Wo^T + deg*bo)  ->  layer-2 q/kv (f16, packed)
// ---------------------------------------------------------------------------
__global__ __launch_bounds__(128) void post_qkv_kernel(
    const float* __restrict__ accum, const int* __restrict__ deg,
    const float* __restrict__ wo, const float* __restrict__ bo,
    const float* __restrict__ wqkv, const float* __restrict__ bqkv,
    ushort* __restrict__ qout, ushort* __restrict__ kvout) {
    __shared__ float swo[16 * 17];
    __shared__ float sbo[16];
    __shared__ float swq[48 * 17];
    __shared__ float sbq[48];
    __shared__ float sa[FD];
    __shared__ float sh[FD];
    __shared__ uint squ[64];
    __shared__ uint skvu[128];
    const int t = threadIdx.x;
    for (int i = t; i < 16 * 16; i += 128) swo[(i >> 4) * 17 + (i & 15)] = wo[i];
    for (int i = t; i < 48 * 16; i += 128) swq[(i >> 4) * 17 + (i & 15)] = wqkv[i];
    if (t < 16) sbo[t] = bo[t];
    if (t < 48) sbq[t] = bqkv[t];
    const int f = t >> 4, d = t & 15, h = d >> 2, dd = d & 3;
    for (int nb = 0; nb < NPB; ++nb) {
        const int n = blockIdx.x * NPB + nb;
        __syncthreads();
        sa[t] = accum[n * FD + t];
        __syncthreads();
        float hv = (float)deg[n] * sbo[d];
#pragma unroll
        for (int e = 0; e < 16; ++e) hv = fmaf(sa[f * 16 + e], swo[d * 17 + e], hv);
        hv = hv > 0.f ? hv : expm1f(hv);
        sh[t] = hv;
        __syncthreads();
        float aq = sbq[d], ak = sbq[16 + d], av = sbq[32 + d];
        const float* xr = &sh[f * 16];
#pragma unroll
        for (int e = 0; e < 16; ++e) {
            const float xe = xr[e];
            aq = fmaf(xe, swq[d * 17 + e], aq);
            ak = fmaf(xe, swq[(16 + d) * 17 + e], ak);
            av = fmaf(xe, swq[(32 + d) * 17 + e], av);
        }
        ushort* sq = (ushort*)squ;
        ushort* skv = (ushort*)skvu;
        sq[t] = f16b(aq * QSCALE);
        skv[h * 64 + f * 4 + dd] = f16b(ak);
        skv[h * 64 + 32 + dd * 8 + f] = f16b(av);
        __syncthreads();
        if (t < 64) ((uint*)(qout + n * FD))[t] = squ[t];
        ((uint*)(kvout + n * 256))[t] = skvu[t];
    }
}

// ---------------------------------------------------------------------------
// Fused: h2 = ELU(accum @ Wo^T + deg*bo) -> logits -> log_softmax -> out
// ---------------------------------------------------------------------------
__global__ __launch_bounds__(128) void post_cls_kernel(
    const float* __restrict__ accum, const int* __restrict__ deg,
    const float* __restrict__ wo, const float* __restrict__ bo,
    const float* __restrict__ cw, const float* __restrict__ cb,
    float* __restrict__ out) {
    __shared__ float swo[16 * 17];
    __shared__ float sbo[16];
    __shared__ float scw[OUTC * FD];
    __shared__ float sa[FD];
    __shared__ float sred[2 * OUTC];
    const int t = threadIdx.x;
    for (int i = t; i < 16 * 16; i += 128) swo[(i >> 4) * 17 + (i & 15)] = wo[i];
    for (int i = t; i < OUTC * FD; i += 128) scw[i] = cw[i];
    if (t < 16) sbo[t] = bo[t];
    const int f = t >> 4, d = t & 15;
    const int lane = t & 63, wid = t >> 6;
    for (int nb = 0; nb < NPB; ++nb) {
        const int n = blockIdx.x * NPB + nb;
        __syncthreads();
        sa[t] = accum[n * FD + t];
        __syncthreads();
        float hv = (float)deg[n] * sbo[d];
#pragma unroll
        for (int e = 0; e < 16; ++e) hv = fmaf(sa[f * 16 + e], swo[d * 17 + e], hv);
        hv = hv > 0.f ? hv : expm1f(hv);
        float p[OUTC];
#pragma unroll
        for (int c = 0; c < OUTC; ++c) p[c] = hv * scw[c * FD + t];
#pragma unroll
        for (int c = 0; c < OUTC; ++c)
            for (int off = 32; off; off >>= 1) p[c] += __shfl_xor(p[c], off);
        if (lane == 0)
#pragma unroll
            for (int c = 0; c < OUTC; ++c) sred[wid * OUTC + c] = p[c];
        __syncthreads();
        if (t == 0) {
            float lg[OUTC];
            float m = -1e30f;
#pragma unroll
            for (int c = 0; c < OUTC; ++c) {
                lg[c] = sred[c] + sred[OUTC + c] + cb[c];
                m = fmaxf(m, lg[c]);
            }
            float s = 0.f;
#pragma unroll
            for (int c = 0; c < OUTC; ++c) s += __expf(lg[c] - m);
            const float lse = m + logf(s);
#pragma unroll
            for (int c = 0; c < OUTC; ++c) out[n * OUTC + c] = lg[c] - lse;
        }
    }
}

extern "C" void kernel_launch(void* const* d_in, const int* in_sizes, int n_in,
                              void* d_out, int out_size, void* d_ws, size_t ws_size,
                              hipStream_t stream) {
    const float* x      = (const float*)d_in[0];
    const int*   ei     = (const int*)d_in[1];
    const float* w1qkv  = (const float*)d_in[2];
    const float* b1qkv  = (const float*)d_in[3];
    const float* w1o    = (const float*)d_in[4];
    const float* b1o    = (const float*)d_in[5];
    const float* w2qkv  = (const float*)d_in[6];
    const float* b2qkv  = (const float*)d_in[7];
    const float* w2o    = (const float*)d_in[8];
    const float* b2o    = (const float*)d_in[9];
    const float* outw   = (const float*)d_in[10];
    const float* outb   = (const float*)d_in[11];
    float* out = (float*)d_out;

    const int* srcp = ei;        // edge_index[0]
    const int* dstp = ei + NE;   // edge_index[1]

    // Workspace: qh f16 (5.12MB), kvh f16 (10.24MB), accum f32 (10.24MB),
    // CSR ints (~1.4MB + 8-int pad for branchless prefetch).
    ushort* qh    = (ushort*)d_ws;
    ushort* kvh   = qh + (size_t)NN * FD;
    float*  accum = (float*)(kvh + (size_t)NN * 256);
    int*    deg      = (int*)(accum + NFD);
    int*    rowstart = deg + NN;          // NN+1 entries
    int*    cursor   = rowstart + NN + 1;
    int*    csr_src  = cursor + NN;       // NE + 8 pad

    // Build CSR (once; shared by both layers)
    (void)hipMemsetAsync(deg, 0, NN * sizeof(int), stream);
    (void)hipMemsetAsync(csr_src + NE, 0, 8 * sizeof(int), stream);
    deg_kernel<<<(NE + 255) / 256, 256, 0, stream>>>(dstp, deg);
    scan_kernel<<<1, 1024, 0, stream>>>(deg, rowstart, cursor);
    scatter_kernel<<<(NE + 255) / 256, 256, 0, stream>>>(srcp, dstp, cursor, csr_src);

    // Layer 1
    qkv1_kernel<<<NN / NPB, 128, 0, stream>>>(x, w1qkv, b1qkv, qh, kvh);
    edge_agg_kernel<<<NN / 4, 256, 0, stream>>>(rowstart, csr_src, qh, (const uint*)kvh, accum);
    // Layer 2 (fused epilogue+projection)
    post_qkv_kernel<<<NN / NPB, 128, 0, stream>>>(accum, deg, w1o, b1o, w2qkv, b2qkv, qh, kvh);
    edge_agg_kernel<<<NN / 4, 256, 0, stream>>>(rowstart, csr_src, qh, (const uint*)kvh, accum);
    // Output head (fused epilogue+classifier)
    post_cls_kernel<<<NN / NPB, 128, 0, stream>>>(accum, deg, w2o, b2o, outw, outb, out);
}